// Round 10
// baseline (148.552 us; speedup 1.0000x reference)
//
#include <hip/hip_runtime.h>
#include <hip/hip_bf16.h>

#define EPS_ODIN 0.0014f

constexpr int Bb  = 1024;
constexpr int Cc  = 100;
constexpr int Dd  = 512;
constexpr int INn = 3072;
constexpr int PITCH = 68;   // shorts; 136B pitch

using s16x8 = __attribute__((ext_vector_type(8))) short;
using s16x4 = __attribute__((ext_vector_type(4))) short;
using f32x4 = __attribute__((ext_vector_type(4))) float;

__device__ __forceinline__ short f2bf(float f) {
    __hip_bfloat16 h = __float2bfloat16(f);
    return *reinterpret_cast<short*>(&h);
}

// ---------------- prep: invsig/mu bf16 planes + W transpose ----------------
__global__ __launch_bounds__(256) void prep_kernel(
    const float* __restrict__ W, const float* __restrict__ invsig, const float* __restrict__ mu,
    short* __restrict__ Wt_b, short* __restrict__ is_b, short* __restrict__ mu_b)
{
    __shared__ float tp[32][33];
    const int tid = threadIdx.x, bid = blockIdx.x;
    const long gstride = (long)gridDim.x * 256;
    auto cvt4 = [&](const float* in, short* ob, long q) {
        long idx = q * 4;
        f32x4 v = *(const f32x4*)(in + idx);
        s16x4 o;
        #pragma unroll
        for (int j = 0; j < 4; ++j) o[j] = f2bf(v[j]);
        *(s16x4*)(ob + idx) = o;
    };
    for (long i = (long)bid * 256 + tid; i < (long)Dd * Dd / 4; i += gstride) cvt4(invsig, is_b, i);
    for (long i = (long)bid * 256 + tid; i < (long)112 * Dd / 4; i += gstride) {
        long idx = i * 4;
        if ((idx >> 9) < Cc) cvt4(mu, mu_b, i);
        else *(s16x4*)(mu_b + idx) = s16x4{0, 0, 0, 0};
    }
    const int tx = tid & 31, ty = tid >> 5;
    for (int tix = bid; tix < (INn / 32) * (Dd / 32); tix += gridDim.x) {
        int r0 = (tix >> 4) * 32, c0 = (tix & 15) * 32;
        #pragma unroll
        for (int i2 = 0; i2 < 4; ++i2)
            tp[ty + i2 * 8][tx] = W[(long)(r0 + ty + i2 * 8) * Dd + c0 + tx];
        __syncthreads();
        #pragma unroll
        for (int i2 = 0; i2 < 4; ++i2) {
            int c = c0 + ty + i2 * 8;
            Wt_b[(long)c * INn + r0 + tx] = f2bf(tp[tx][ty + i2 * 8]);
        }
        __syncthreads();
    }
}

// ---------------- im = mu @ invsig (fp32 exact) ; q[c] = mu_c . im_c ----------------
__global__ __launch_bounds__(256) void im_q_kernel(
    const float* __restrict__ mu, const float* __restrict__ invsig,
    float* __restrict__ im, float* __restrict__ q)
{
    __shared__ float muc[512];
    __shared__ float red[4];
    const int tid = threadIdx.x, c = blockIdx.x;
    for (int e = tid; e < 512; e += 256) muc[e] = mu[(long)c * 512 + e];
    __syncthreads();
    const int d0 = tid, d1 = tid + 256;
    float a0 = 0.f, a1 = 0.f, a2 = 0.f, a3 = 0.f;
    for (int e = 0; e < 512; e += 2) {
        float m0 = muc[e], m1 = muc[e + 1];
        a0 = fmaf(m0, invsig[(long)e * 512 + d0], a0);
        a1 = fmaf(m0, invsig[(long)e * 512 + d1], a1);
        a2 = fmaf(m1, invsig[(long)(e + 1) * 512 + d0], a2);
        a3 = fmaf(m1, invsig[(long)(e + 1) * 512 + d1], a3);
    }
    float r0 = a0 + a2, r1 = a1 + a3;
    im[(long)c * 512 + d0] = r0;
    im[(long)c * 512 + d1] = r1;
    float s = muc[d0] * r0 + muc[d1] * r1;
    #pragma unroll
    for (int off = 32; off; off >>= 1) s += __shfl_down(s, off);
    if ((tid & 63) == 0) red[tid >> 6] = s;
    __syncthreads();
    if (tid == 0) q[c] = red[0] + red[1] + red[2] + red[3];
}

// ---------------- 128x64 split-K partials GEMM; A fp32 (inline cvt) ----------------
template<bool AF32>
__global__ __launch_bounds__(256, 4) void gemm_part(
    const void* __restrict__ Av, const short* __restrict__ Bm,
    float* __restrict__ Cm, long K, int kcount, long sstr)
{
    __shared__ short As[128 * PITCH];
    __shared__ short Bs[64 * PITCH];
    const short* A  = (const short*)Av;
    const float* Af = (const float*)Av;
    const int tid = threadIdx.x;
    const int m0 = blockIdx.y * 128, n0 = blockIdx.x * 64;
    const long kbeg = (long)blockIdx.z * kcount;
    const int lane = tid & 63, w = tid >> 6, wm = w * 32;
    const int lrow = lane & 15, kseg = lane >> 4;
    const int srow = tid >> 3, skc = (tid & 7) * 8;
    const int nkt = kcount >> 6;

    f32x4 acc[2][4];
    #pragma unroll
    for (int i = 0; i < 2; ++i)
        #pragma unroll
        for (int j = 0; j < 4; ++j)
            acc[i][j] = f32x4{0.f, 0.f, 0.f, 0.f};

    s16x8 rA[4], rB[2];
    f32x4 rAf[4][2];
    auto ldA = [&](int kt) {
        #pragma unroll
        for (int i = 0; i < 4; ++i) {
            long off = (long)(m0 + srow + i * 32) * K + kbeg + (long)kt * 64 + skc;
            if (AF32) { rAf[i][0] = *(const f32x4*)(Af + off); rAf[i][1] = *(const f32x4*)(Af + off + 4); }
            else      { rA[i] = *(const s16x8*)(A + off); }
        }
    };
    auto ldB = [&](int kt) {
        #pragma unroll
        for (int i = 0; i < 2; ++i)
            rB[i] = *(const s16x8*)(Bm + (long)(n0 + srow + i * 32) * K + kbeg + (long)kt * 64 + skc);
    };

    ldA(0); ldB(0);
    for (int kt = 0; kt < nkt; ++kt) {
        #pragma unroll
        for (int i = 0; i < 4; ++i) {
            if (AF32) {
                s16x8 o;
                #pragma unroll
                for (int j = 0; j < 4; ++j) { o[j] = f2bf(rAf[i][0][j]); o[4 + j] = f2bf(rAf[i][1][j]); }
                *(s16x8*)&As[(srow + i * 32) * PITCH + skc] = o;
            } else {
                *(s16x8*)&As[(srow + i * 32) * PITCH + skc] = rA[i];
            }
        }
        #pragma unroll
        for (int i = 0; i < 2; ++i)
            *(s16x8*)&Bs[(srow + i * 32) * PITCH + skc] = rB[i];
        __syncthreads();
        if (kt + 1 < nkt) { ldA(kt + 1); ldB(kt + 1); }
        #pragma unroll
        for (int kk = 0; kk < 2; ++kk) {
            s16x8 ah[2], bfr[4];
            #pragma unroll
            for (int i = 0; i < 2; ++i)
                ah[i] = *(const s16x8*)&As[(wm + i * 16 + lrow) * PITCH + kk * 32 + kseg * 8];
            #pragma unroll
            for (int j = 0; j < 4; ++j)
                bfr[j] = *(const s16x8*)&Bs[(j * 16 + lrow) * PITCH + kk * 32 + kseg * 8];
            #pragma unroll
            for (int i = 0; i < 2; ++i)
                #pragma unroll
                for (int j = 0; j < 4; ++j)
                    acc[i][j] = __builtin_amdgcn_mfma_f32_16x16x32_bf16(ah[i], bfr[j], acc[i][j], 0, 0, 0);
        }
        __syncthreads();
    }

    const int crow = (lane >> 4) * 4, ccol = lane & 15;
    float* dst = Cm + (long)blockIdx.z * sstr;
    #pragma unroll
    for (int i = 0; i < 2; ++i)
        #pragma unroll
        for (int j = 0; j < 4; ++j)
            #pragma unroll
            for (int r = 0; r < 4; ++r)
                dst[(long)(m0 + wm + i * 16 + crow + r) * 512 + n0 + j * 16 + ccol] = acc[i][j][r];
}

// ---------------- WtW partials: upper-triangle tiles, direct + mirrored writes ----------------
__global__ __launch_bounds__(256, 4) void wtw_part(
    const short* __restrict__ Wt_b, float* __restrict__ wpart)
{
    __shared__ short As[128 * PITCH];
    __shared__ short Bs[64 * PITCH];
    const int tid = threadIdx.x;
    int t = blockIdx.x, tm, tn;
    if (t < 8)       { tm = 0; tn = t; }
    else if (t < 14) { tm = 1; tn = t - 6; }
    else if (t < 18) { tm = 2; tn = t - 10; }
    else             { tm = 3; tn = t - 12; }
    const int m0 = tm * 128, n0 = tn * 64;
    const long kbeg = (long)blockIdx.y * 384;
    const int lane = tid & 63, w = tid >> 6, wm = w * 32;
    const int lrow = lane & 15, kseg = lane >> 4;
    const int srow = tid >> 3, skc = (tid & 7) * 8;

    f32x4 acc[2][4];
    #pragma unroll
    for (int i = 0; i < 2; ++i)
        #pragma unroll
        for (int j = 0; j < 4; ++j)
            acc[i][j] = f32x4{0.f, 0.f, 0.f, 0.f};

    s16x8 rA[4], rB[2];
    auto ldA = [&](int kt) {
        #pragma unroll
        for (int i = 0; i < 4; ++i)
            rA[i] = *(const s16x8*)(Wt_b + (long)(m0 + srow + i * 32) * INn + kbeg + (long)kt * 64 + skc);
    };
    auto ldB = [&](int kt) {
        #pragma unroll
        for (int i = 0; i < 2; ++i)
            rB[i] = *(const s16x8*)(Wt_b + (long)(n0 + srow + i * 32) * INn + kbeg + (long)kt * 64 + skc);
    };

    ldA(0); ldB(0);
    for (int kt = 0; kt < 6; ++kt) {
        #pragma unroll
        for (int i = 0; i < 4; ++i)
            *(s16x8*)&As[(srow + i * 32) * PITCH + skc] = rA[i];
        #pragma unroll
        for (int i = 0; i < 2; ++i)
            *(s16x8*)&Bs[(srow + i * 32) * PITCH + skc] = rB[i];
        __syncthreads();
        if (kt + 1 < 6) { ldA(kt + 1); ldB(kt + 1); }
        #pragma unroll
        for (int kk = 0; kk < 2; ++kk) {
            s16x8 ah[2], bfr[4];
            #pragma unroll
            for (int i = 0; i < 2; ++i)
                ah[i] = *(const s16x8*)&As[(wm + i * 16 + lrow) * PITCH + kk * 32 + kseg * 8];
            #pragma unroll
            for (int j = 0; j < 4; ++j)
                bfr[j] = *(const s16x8*)&Bs[(j * 16 + lrow) * PITCH + kk * 32 + kseg * 8];
            #pragma unroll
            for (int i = 0; i < 2; ++i)
                #pragma unroll
                for (int j = 0; j < 4; ++j)
                    acc[i][j] = __builtin_amdgcn_mfma_f32_16x16x32_bf16(ah[i], bfr[j], acc[i][j], 0, 0, 0);
        }
        __syncthreads();
    }

    const int crow = (lane >> 4) * 4, ccol = lane & 15;
    float* dst = wpart + (long)blockIdx.y * Dd * Dd;
    #pragma unroll
    for (int i = 0; i < 2; ++i)
        #pragma unroll
        for (int j = 0; j < 4; ++j)
            #pragma unroll
            for (int r = 0; r < 4; ++r) {
                int gm = m0 + wm + i * 16 + crow + r;
                int gn = n0 + j * 16 + ccol;
                float v = acc[i][j][r];
                dst[(long)gm * 512 + gn] = v;
                dst[(long)gn * 512 + gm] = v;
            }
}

// ---------------- reduce 8 split-K slabs + bias + relu -> featpre, feat fp32 + bf16 ----------------
__global__ __launch_bounds__(256) void reduce_feat(
    const float* __restrict__ part, const float* __restrict__ bias,
    float* __restrict__ featpre, float* __restrict__ feat, short* __restrict__ fb)
{
    long idx = ((long)blockIdx.x * 256 + threadIdx.x) * 4;
    f32x4 v = *(const f32x4*)(part + idx);
    #pragma unroll
    for (int z = 1; z < 8; ++z)
        v += *(const f32x4*)(part + (long)z * Bb * Dd + idx);
    *(f32x4*)(featpre + idx) = v;
    f32x4 bb = *(const f32x4*)(bias + (idx & 511));
    s16x4 o;
    #pragma unroll
    for (int j = 0; j < 4; ++j) {
        v[j] = fmaxf(v[j] + bb[j], 0.f);
        o[j] = f2bf(v[j]);
    }
    *(f32x4*)(feat + idx) = v;
    *(s16x4*)(fb + idx) = o;
}

// ---------------- reduce 8 WtW slabs -> bf16 ----------------
__global__ __launch_bounds__(256) void reduce_wtw(
    const float* __restrict__ wpart, short* __restrict__ wtw_b)
{
    long idx = ((long)blockIdx.x * 256 + threadIdx.x) * 4;
    f32x4 v = *(const f32x4*)(wpart + idx);
    #pragma unroll
    for (int z = 1; z < 8; ++z)
        v += *(const f32x4*)(wpart + (long)z * Dd * Dd + idx);
    s16x4 o;
    #pragma unroll
    for (int j = 0; j < 4; ++j) o[j] = f2bf(v[j]);
    *(s16x4*)(wtw_b + idx) = o;
}

// ---------------- fused A: h = feat@invsig (regs) -> t = h@mu^T -> argmax -> dz ----------------
// 64 blocks x 16 rows. 4 waves; wave w owns output cols [w*128, w*128+128) of h.
__global__ __launch_bounds__(256) void fused_a(
    const short* __restrict__ f_b, const short* __restrict__ is_b,
    const short* __restrict__ mu_b, const float* __restrict__ feat,
    const float* __restrict__ im, const float* __restrict__ q,
    short* __restrict__ dz_b)
{
    __shared__ short hstage[4][2][16][68];
    __shared__ f32x4 red[4][7][64];
    __shared__ int cstv[16];
    const int tid = threadIdx.x, lane = tid & 63, w = tid >> 6;
    const int m0 = blockIdx.x * 16;
    const int arow = lane & 15, kseg = lane >> 4;
    const int wn = w * 128;
    const int crow = (lane >> 4) * 4, ccol = lane & 15;

    // Phase 1: h (fp32, registers)
    f32x4 hreg[8];
    #pragma unroll
    for (int j = 0; j < 8; ++j) hreg[j] = f32x4{0.f, 0.f, 0.f, 0.f};
    for (int kt = 0; kt < 16; ++kt) {
        s16x8 av = *(const s16x8*)(f_b + (long)(m0 + arow) * 512 + kt * 32 + kseg * 8);
        #pragma unroll
        for (int j = 0; j < 8; ++j) {
            s16x8 bv = *(const s16x8*)(is_b + (long)(wn + j * 16 + arow) * 512 + kt * 32 + kseg * 8);
            hreg[j] = __builtin_amdgcn_mfma_f32_16x16x32_bf16(av, bv, hreg[j], 0, 0, 0);
        }
    }
    // Phase 2: stage own h slice (bf16) for the t-step A-fragments
    #pragma unroll
    for (int j = 0; j < 8; ++j) {
        int nloc = j * 16 + ccol;
        #pragma unroll
        for (int r = 0; r < 4; ++r)
            hstage[w][nloc >> 6][crow + r][nloc & 63] = f2bf(hreg[j][r]);
    }
    __syncthreads();
    f32x4 tacc[7];
    #pragma unroll
    for (int j = 0; j < 7; ++j) tacc[j] = f32x4{0.f, 0.f, 0.f, 0.f};
    #pragma unroll
    for (int kt = 0; kt < 4; ++kt) {
        int k = kt * 32 + kseg * 8;
        s16x8 av = *(const s16x8*)&hstage[w][k >> 6][arow][k & 63];
        #pragma unroll
        for (int j = 0; j < 7; ++j) {
            s16x8 bv = *(const s16x8*)(mu_b + (long)(j * 16 + arow) * 512 + wn + k);
            tacc[j] = __builtin_amdgcn_mfma_f32_16x16x32_bf16(av, bv, tacc[j], 0, 0, 0);
        }
    }
    #pragma unroll
    for (int j = 0; j < 7; ++j) red[w][j][lane] = tacc[j];
    __syncthreads();

    if (w == 0) {
        #pragma unroll
        for (int j = 0; j < 7; ++j) {
            f32x4 s0 = red[0][j][lane];
            #pragma unroll
            for (int ww = 1; ww < 4; ++ww) s0 += red[ww][j][lane];
            tacc[j] = s0;
        }
        #pragma unroll
        for (int r = 0; r < 4; ++r) {
            float best = -INFINITY; int bestc = 0;
            #pragma unroll
            for (int j = 0; j < 7; ++j) {
                int n = j * 16 + ccol;
                if (n < 100) {
                    float v = 2.f * tacc[j][r] - q[n];
                    if (v > best) { best = v; bestc = n; }
                }
            }
            #pragma unroll
            for (int mk = 1; mk <= 8; mk <<= 1) {
                float ov = __shfl_xor(best, mk);
                int   oc = __shfl_xor(bestc, mk);
                if (ov > best || (ov == best && oc < bestc)) { best = ov; bestc = oc; }
            }
            if (ccol == 0) cstv[crow + r] = bestc;
        }
    }
    __syncthreads();

    // Phase 4: dz from register h
    #pragma unroll
    for (int j = 0; j < 8; ++j)
        #pragma unroll
        for (int r = 0; r < 4; ++r) {
            int gm = m0 + crow + r, gn = wn + j * 16 + ccol;
            long gi = (long)gm * 512 + gn;
            float fv = feat[gi];
            float v = (fv > 0.f) ? -2.f * (hreg[j][r] - im[(long)cstv[crow + r] * 512 + gn]) : 0.f;
            dz_b[gi] = f2bf(v);
        }
}

// ---------------- fused B: feat2 -> h2 -> s -> t2 -> out ----------------
__global__ __launch_bounds__(256) void fused_b(
    const short* __restrict__ dz_b, const short* __restrict__ wtw_b,
    const short* __restrict__ is_b, const short* __restrict__ mu_b,
    const float* __restrict__ featpre, const float* __restrict__ bias,
    const float* __restrict__ q, float* __restrict__ out)
{
    __shared__ short xch[8][16][68];   // phase0/1: full feat2 bf16; phase3: per-wave h2 staging (aliased)
    __shared__ f32x4 red[4][7][64];
    __shared__ float sred[4][16];
    const int tid = threadIdx.x, lane = tid & 63, w = tid >> 6;
    const int m0 = blockIdx.x * 16;
    const int arow = lane & 15, kseg = lane >> 4;
    const int wn = w * 128;
    const int crow = (lane >> 4) * 4, ccol = lane & 15;

    // Phase 0: feat2 = relu(featpre + bias + eps * dz@WtW)  (fp32 in regs)
    f32x4 f2[8];
    #pragma unroll
    for (int j = 0; j < 8; ++j) f2[j] = f32x4{0.f, 0.f, 0.f, 0.f};
    for (int kt = 0; kt < 16; ++kt) {
        s16x8 av = *(const s16x8*)(dz_b + (long)(m0 + arow) * 512 + kt * 32 + kseg * 8);
        #pragma unroll
        for (int j = 0; j < 8; ++j) {
            s16x8 bv = *(const s16x8*)(wtw_b + (long)(wn + j * 16 + arow) * 512 + kt * 32 + kseg * 8);
            f2[j] = __builtin_amdgcn_mfma_f32_16x16x32_bf16(av, bv, f2[j], 0, 0, 0);
        }
    }
    #pragma unroll
    for (int j = 0; j < 8; ++j) {
        int gn = wn + j * 16 + ccol;
        #pragma unroll
        for (int r = 0; r < 4; ++r) {
            float u = fmaxf(featpre[(long)(m0 + crow + r) * 512 + gn] + bias[gn] + EPS_ODIN * f2[j][r], 0.f);
            f2[j][r] = u;
            xch[gn >> 6][crow + r][gn & 63] = f2bf(u);
        }
    }
    __syncthreads();

    // Phase 1: h2 = feat2 @ invsig (fp32 regs)
    f32x4 h2[8];
    #pragma unroll
    for (int j = 0; j < 8; ++j) h2[j] = f32x4{0.f, 0.f, 0.f, 0.f};
    for (int kt = 0; kt < 16; ++kt) {
        int k = kt * 32 + kseg * 8;
        s16x8 av = *(const s16x8*)&xch[k >> 6][arow][k & 63];
        #pragma unroll
        for (int j = 0; j < 8; ++j) {
            s16x8 bv = *(const s16x8*)(is_b + (long)(wn + j * 16 + arow) * 512 + k);
            h2[j] = __builtin_amdgcn_mfma_f32_16x16x32_bf16(av, bv, h2[j], 0, 0, 0);
        }
    }

    // Phase 2: s partials — f2 and h2 share the exact fragment layout
    float sloc[4] = {0.f, 0.f, 0.f, 0.f};
    #pragma unroll
    for (int j = 0; j < 8; ++j)
        #pragma unroll
        for (int r = 0; r < 4; ++r)
            sloc[r] += f2[j][r] * h2[j][r];
    #pragma unroll
    for (int r = 0; r < 4; ++r) {
        #pragma unroll
        for (int mk = 1; mk <= 8; mk <<= 1)
            sloc[r] += __shfl_xor(sloc[r], mk);
    }
    if (ccol == 0) {
        #pragma unroll
        for (int r = 0; r < 4; ++r) sred[w][crow + r] = sloc[r];
    }
    __syncthreads();   // all phase-1 xch reads done; sred visible

    // Phase 3: re-stage own h2 slice (bf16) into aliased xch region
    {
        short* hst = &xch[w * 2][0][0];   // [2][16][68] per wave
        #pragma unroll
        for (int j = 0; j < 8; ++j) {
            int nloc = j * 16 + ccol;
            #pragma unroll
            for (int r = 0; r < 4; ++r)
                hst[(nloc >> 6) * (16 * 68) + (crow + r) * 68 + (nloc & 63)] = f2bf(h2[j][r]);
        }
    }
    __syncthreads();
    f32x4 tacc[7];
    #pragma unroll
    for (int j = 0; j < 7; ++j) tacc[j] = f32x4{0.f, 0.f, 0.f, 0.f};
    {
        const short* hst = &xch[w * 2][0][0];
        #pragma unroll
        for (int kt = 0; kt < 4; ++kt) {
            int k = kt * 32 + kseg * 8;
            s16x8 av = *(const s16x8*)&hst[(k >> 6) * (16 * 68) + arow * 68 + (k & 63)];
            #pragma unroll
            for (int j = 0; j < 7; ++j) {
                s16x8 bv = *(const s16x8*)(mu_b + (long)(j * 16 + arow) * 512 + wn + k);
                tacc[j] = __builtin_amdgcn_mfma_f32_16x16x32_bf16(av, bv, tacc[j], 0, 0, 0);
            }
        }
    }
    #pragma unroll
    for (int j = 0; j < 7; ++j) red[w][j][lane] = tacc[j];
    __syncthreads();

    if (w == 0) {
        #pragma unroll
        for (int j = 0; j < 7; ++j) {
            int n = j * 16 + ccol;
            if (n >= 100) continue;
            f32x4 s0 = red[0][j][lane];
            #pragma unroll
            for (int ww = 1; ww < 4; ++ww) s0 += red[ww][j][lane];
            float qn = q[n];
            #pragma unroll
            for (int r = 0; r < 4; ++r) {
                int row = crow + r;
                float sv = sred[0][row] + sred[1][row] + sred[2][row] + sred[3][row];
                out[(long)(m0 + row) * 100 + n] = 2.f * s0[r] - sv - qn;
            }
        }
    }
}

extern "C" void kernel_launch(void* const* d_in, const int* in_sizes, int n_in,
                              void* d_out, int out_size, void* d_ws, size_t ws_size,
                              hipStream_t stream)
{
    const float* x      = (const float*)d_in[0];
    const float* W      = (const float*)d_in[1];
    const float* bias   = (const float*)d_in[2];
    const float* mu     = (const float*)d_in[3];
    const float* invsig = (const float*)d_in[4];
    float* out = (float*)d_out;

    char* wp = (char*)d_ws;
    auto alloc = [&](size_t bytes) { char* p = wp; wp += (bytes + 255) & ~size_t(255); return p; };
    short* Wt_b  = (short*)alloc((size_t)Dd * INn * 2);
    short* is_b  = (short*)alloc((size_t)Dd * Dd * 2);
    short* mu_b  = (short*)alloc((size_t)112 * Dd * 2);   // zero-padded to 112 rows
    short* wtw_b = (short*)alloc((size_t)Dd * Dd * 2);
    float* im    = (float*)alloc((size_t)Cc * Dd * 4);
    float* q     = (float*)alloc(512);
    float* part  = (float*)alloc((size_t)8 * Bb * Dd * 4);
    float* wpart = (float*)alloc((size_t)8 * Dd * Dd * 4);
    float* featpre = (float*)alloc((size_t)Bb * Dd * 4);
    float* feat  = (float*)alloc((size_t)Bb * Dd * 4);
    short* f_b   = (short*)alloc((size_t)Bb * Dd * 2);
    short* dz_b  = (short*)alloc((size_t)Bb * Dd * 2);

    dim3 blk(256);

    // 1. bf16 planes (invsig, mu) + W transpose
    prep_kernel<<<256, blk, 0, stream>>>(W, invsig, mu, Wt_b, is_b, mu_b);
    // 2. im (fp32 exact) + q
    im_q_kernel<<<Cc, blk, 0, stream>>>(mu, invsig, im, q);
    // 3. WtW partials (upper-triangle, split-K8)
    wtw_part<<<dim3(20, 8), blk, 0, stream>>>(Wt_b, wpart);
    // 4. reduce WtW -> bf16
    reduce_wtw<<<256, blk, 0, stream>>>(wpart, wtw_b);
    // 5. feat partials: x(fp32 inline cvt) @ W split-K8 (512 blocks)
    gemm_part<true><<<dim3(8, 8, 8), blk, 0, stream>>>(
        (const void*)x, Wt_b, part, INn, INn / 8, (long)Bb * Dd);
    // 6. reduce + bias + relu -> featpre, feat, f_b
    reduce_feat<<<512, blk, 0, stream>>>(part, bias, featpre, feat, f_b);
    // 7. fused A: h -> t -> argmax -> dz
    fused_a<<<Bb / 16, blk, 0, stream>>>(f_b, is_b, mu_b, feat, im, q, dz_b);
    // 8. fused B: feat2 -> h2 -> s -> t2 -> out
    fused_b<<<Bb / 16, blk, 0, stream>>>(dz_b, wtw_b, is_b, mu_b, featpre, bias, q, out);
}

// Round 11
// 108.768 us; speedup vs baseline: 1.3658x; 1.3658x over previous
//
#include <hip/hip_runtime.h>
#include <hip/hip_bf16.h>

#define EPS_ODIN 0.0014f

constexpr int Bb  = 1024;
constexpr int Cc  = 100;
constexpr int Dd  = 512;
constexpr int INn = 3072;
constexpr int PITCH = 68;   // shorts; 136B pitch

using s16x8 = __attribute__((ext_vector_type(8))) short;
using s16x4 = __attribute__((ext_vector_type(4))) short;
using f32x4 = __attribute__((ext_vector_type(4))) float;

__device__ __forceinline__ short f2bf(float f) {
    __hip_bfloat16 h = __float2bfloat16(f);
    return *reinterpret_cast<short*>(&h);
}

// ---------------- prep: fp32 -> bf16 planes + W transpose; mu padded to 112 rows ----------------
__global__ __launch_bounds__(256) void prep_kernel(
    const float* __restrict__ x, const float* __restrict__ W,
    const float* __restrict__ invsig, const float* __restrict__ mu,
    short* __restrict__ x_b, short* __restrict__ Wt_b,
    short* __restrict__ is_b, short* __restrict__ mu_b)
{
    __shared__ float tp[32][33];
    const int tid = threadIdx.x, bid = blockIdx.x;
    const long gstride = (long)gridDim.x * 256;
    auto cvt4 = [&](const float* in, short* ob, long q) {
        long idx = q * 4;
        f32x4 v = *(const f32x4*)(in + idx);
        s16x4 o;
        #pragma unroll
        for (int j = 0; j < 4; ++j) o[j] = f2bf(v[j]);
        *(s16x4*)(ob + idx) = o;
    };
    for (long i = (long)bid * 256 + tid; i < (long)Bb * INn / 4; i += gstride) cvt4(x, x_b, i);
    for (long i = (long)bid * 256 + tid; i < (long)Dd * Dd / 4; i += gstride) cvt4(invsig, is_b, i);
    for (long i = (long)bid * 256 + tid; i < (long)112 * Dd / 4; i += gstride) {
        long idx = i * 4;
        if ((idx >> 9) < Cc) cvt4(mu, mu_b, i);
        else *(s16x4*)(mu_b + idx) = s16x4{0, 0, 0, 0};
    }

    const int tx = tid & 31, ty = tid >> 5;
    for (int tix = bid; tix < (INn / 32) * (Dd / 32); tix += gridDim.x) {
        int r0 = (tix >> 4) * 32, c0 = (tix & 15) * 32;
        #pragma unroll
        for (int i2 = 0; i2 < 4; ++i2)
            tp[ty + i2 * 8][tx] = W[(long)(r0 + ty + i2 * 8) * Dd + c0 + tx];
        __syncthreads();
        #pragma unroll
        for (int i2 = 0; i2 < 4; ++i2) {
            int c = c0 + ty + i2 * 8;
            Wt_b[(long)c * INn + r0 + tx] = f2bf(tp[tx][ty + i2 * 8]);
        }
        __syncthreads();
    }
}

// ---------------- im = mu @ invsig (fp32 exact) ; q[c] = mu_c . im_c ----------------
__global__ __launch_bounds__(256) void im_q_kernel(
    const float* __restrict__ mu, const float* __restrict__ invsig,
    float* __restrict__ im, float* __restrict__ q)
{
    __shared__ float muc[512];
    __shared__ float red[4];
    const int tid = threadIdx.x, c = blockIdx.x;
    for (int e = tid; e < 512; e += 256) muc[e] = mu[(long)c * 512 + e];
    __syncthreads();
    const int d0 = tid, d1 = tid + 256;
    float a0 = 0.f, a1 = 0.f, a2 = 0.f, a3 = 0.f;
    for (int e = 0; e < 512; e += 2) {
        float m0 = muc[e], m1 = muc[e + 1];
        a0 = fmaf(m0, invsig[(long)e * 512 + d0], a0);
        a1 = fmaf(m0, invsig[(long)e * 512 + d1], a1);
        a2 = fmaf(m1, invsig[(long)(e + 1) * 512 + d0], a2);
        a3 = fmaf(m1, invsig[(long)(e + 1) * 512 + d1], a3);
    }
    float r0 = a0 + a2, r1 = a1 + a3;
    im[(long)c * 512 + d0] = r0;
    im[(long)c * 512 + d1] = r1;
    float s = muc[d0] * r0 + muc[d1] * r1;
    #pragma unroll
    for (int off = 32; off; off >>= 1) s += __shfl_down(s, off);
    if ((tid & 63) == 0) red[tid >> 6] = s;
    __syncthreads();
    if (tid == 0) q[c] = red[0] + red[1] + red[2] + red[3];
}

// ---------------- single-plane bf16 GEMM, 128x64 tile, BK=64 ----------------
// C = A[M,K] @ B^T, B given [N,K].
// EPI 0 -> partial slab (z, stride sstr); 1 -> fp32 + bf16; 3 -> feat2 = relu(aux1+aux2[n]+esc*acc)
template<int EPI>
__global__ __launch_bounds__(256, 4) void gemm_b1(
    const short* __restrict__ A, const short* __restrict__ Bm,
    float* __restrict__ Cm, long K, int kcount, int N, long sstr,
    const float* __restrict__ aux1, const float* __restrict__ aux2,
    short* __restrict__ obf, float esc)
{
    __shared__ short As[128 * PITCH];
    __shared__ short Bs[64 * PITCH];
    const int tid = threadIdx.x;
    const int m0 = blockIdx.y * 128, n0 = blockIdx.x * 64;
    const long kbeg = (long)blockIdx.z * kcount;
    const int lane = tid & 63, w = tid >> 6, wm = w * 32;
    const int lrow = lane & 15, kseg = lane >> 4;
    const int srow = tid >> 3, skc = (tid & 7) * 8;
    const int nkt = kcount >> 6;

    f32x4 acc[2][4];
    #pragma unroll
    for (int i = 0; i < 2; ++i)
        #pragma unroll
        for (int j = 0; j < 4; ++j)
            acc[i][j] = f32x4{0.f, 0.f, 0.f, 0.f};

    s16x8 rA[4], rB[2];
    auto ldA = [&](int kt) {
        #pragma unroll
        for (int i = 0; i < 4; ++i)
            rA[i] = *(const s16x8*)(A + (long)(m0 + srow + i * 32) * K + kbeg + (long)kt * 64 + skc);
    };
    auto ldB = [&](int kt) {
        #pragma unroll
        for (int i = 0; i < 2; ++i)
            rB[i] = *(const s16x8*)(Bm + (long)(n0 + srow + i * 32) * K + kbeg + (long)kt * 64 + skc);
    };

    ldA(0); ldB(0);
    for (int kt = 0; kt < nkt; ++kt) {
        #pragma unroll
        for (int i = 0; i < 4; ++i)
            *(s16x8*)&As[(srow + i * 32) * PITCH + skc] = rA[i];
        #pragma unroll
        for (int i = 0; i < 2; ++i)
            *(s16x8*)&Bs[(srow + i * 32) * PITCH + skc] = rB[i];
        __syncthreads();
        if (kt + 1 < nkt) { ldA(kt + 1); ldB(kt + 1); }
        #pragma unroll
        for (int kk = 0; kk < 2; ++kk) {
            s16x8 ah[2], bfr[4];
            #pragma unroll
            for (int i = 0; i < 2; ++i)
                ah[i] = *(const s16x8*)&As[(wm + i * 16 + lrow) * PITCH + kk * 32 + kseg * 8];
            #pragma unroll
            for (int j = 0; j < 4; ++j)
                bfr[j] = *(const s16x8*)&Bs[(j * 16 + lrow) * PITCH + kk * 32 + kseg * 8];
            #pragma unroll
            for (int i = 0; i < 2; ++i)
                #pragma unroll
                for (int j = 0; j < 4; ++j)
                    acc[i][j] = __builtin_amdgcn_mfma_f32_16x16x32_bf16(ah[i], bfr[j], acc[i][j], 0, 0, 0);
        }
        __syncthreads();
    }

    const int crow = (lane >> 4) * 4, ccol = lane & 15;
    #pragma unroll
    for (int i = 0; i < 2; ++i)
        #pragma unroll
        for (int j = 0; j < 4; ++j)
            #pragma unroll
            for (int r = 0; r < 4; ++r) {
                int gm = m0 + wm + i * 16 + crow + r;
                int gn = n0 + j * 16 + ccol;
                float v = acc[i][j][r];
                if (EPI == 0) {
                    (Cm + (long)blockIdx.z * sstr)[(long)gm * 512 + gn] = v;
                } else if (EPI == 1) {
                    long cidx = (long)gm * N + gn;
                    Cm[cidx] = v;
                    obf[cidx] = f2bf(v);
                } else {
                    long cidx = (long)gm * N + gn;
                    float u = fmaxf(aux1[cidx] + aux2[gn] + esc * v, 0.f);
                    Cm[cidx] = u;
                    obf[cidx] = f2bf(u);
                }
            }
}

// ---------------- reduce 4 split-K slabs + bias + relu -> featpre, feat fp32 + bf16 ----------------
__global__ __launch_bounds__(256) void reduce_feat(
    const float* __restrict__ part, const float* __restrict__ bias,
    float* __restrict__ featpre, float* __restrict__ feat, short* __restrict__ fb)
{
    long idx = ((long)blockIdx.x * 256 + threadIdx.x) * 4;
    f32x4 v = *(const f32x4*)(part + idx);
    #pragma unroll
    for (int z = 1; z < 4; ++z)
        v += *(const f32x4*)(part + (long)z * Bb * Dd + idx);
    *(f32x4*)(featpre + idx) = v;
    f32x4 bb = *(const f32x4*)(bias + (idx & 511));
    s16x4 o;
    #pragma unroll
    for (int j = 0; j < 4; ++j) {
        v[j] = fmaxf(v[j] + bb[j], 0.f);
        o[j] = f2bf(v[j]);
    }
    *(f32x4*)(feat + idx) = v;
    *(s16x4*)(fb + idx) = o;
}

// ---------------- reduce 4 WtW slabs -> bf16 ----------------
__global__ __launch_bounds__(256) void reduce_wtw(
    const float* __restrict__ wpart, short* __restrict__ wtw_b)
{
    long idx = ((long)blockIdx.x * 256 + threadIdx.x) * 4;
    f32x4 v = *(const f32x4*)(wpart + idx);
    #pragma unroll
    for (int z = 1; z < 4; ++z)
        v += *(const f32x4*)(wpart + (long)z * Dd * Dd + idx);
    s16x4 o;
    #pragma unroll
    for (int j = 0; j < 4; ++j) o[j] = f2bf(v[j]);
    *(s16x4*)(wtw_b + idx) = o;
}

// ---------------- tail A: t = h@mu^T, argmax(2t-q) -> dz bf16 ----------------
__global__ __launch_bounds__(256) void tail_a(
    const short* __restrict__ h_b, const short* __restrict__ mu_b,
    const float* __restrict__ feat, const float* __restrict__ hbuf,
    const float* __restrict__ im, const float* __restrict__ q,
    short* __restrict__ dz_b)
{
    __shared__ f32x4 red[4][7][64];
    __shared__ int cstv[16];
    const int tid = threadIdx.x, lane = tid & 63, w = tid >> 6;
    const int m0 = blockIdx.x * 16;
    const int arow = lane & 15, kseg = lane >> 4;

    f32x4 acc[7];
    #pragma unroll
    for (int j = 0; j < 7; ++j) acc[j] = f32x4{0.f, 0.f, 0.f, 0.f};

    const long abase = (long)(m0 + arow) * 512 + w * 128 + kseg * 8;
    const long bbase = (long)arow * 512 + w * 128 + kseg * 8;
    #pragma unroll
    for (int kt = 0; kt < 4; ++kt) {
        s16x8 av = *(const s16x8*)(h_b + abase + kt * 32);
        #pragma unroll
        for (int j = 0; j < 7; ++j) {
            s16x8 bv = *(const s16x8*)(mu_b + bbase + (long)j * 16 * 512 + kt * 32);
            acc[j] = __builtin_amdgcn_mfma_f32_16x16x32_bf16(av, bv, acc[j], 0, 0, 0);
        }
    }
    #pragma unroll
    for (int j = 0; j < 7; ++j) red[w][j][lane] = acc[j];
    __syncthreads();

    if (w == 0) {
        #pragma unroll
        for (int j = 0; j < 7; ++j) {
            f32x4 s0 = red[0][j][lane];
            #pragma unroll
            for (int ww = 1; ww < 4; ++ww) s0 += red[ww][j][lane];
            acc[j] = s0;
        }
        const int crow = (lane >> 4) * 4, ccol = lane & 15;
        #pragma unroll
        for (int r = 0; r < 4; ++r) {
            float best = -INFINITY; int bestc = 0;
            #pragma unroll
            for (int j = 0; j < 7; ++j) {
                int n = j * 16 + ccol;
                if (n < 100) {
                    float v = 2.f * acc[j][r] - q[n];
                    if (v > best) { best = v; bestc = n; }
                }
            }
            #pragma unroll
            for (int mk = 1; mk <= 8; mk <<= 1) {
                float ov = __shfl_xor(best, mk);
                int   oc = __shfl_xor(bestc, mk);
                if (ov > best || (ov == best && oc < bestc)) { best = ov; bestc = oc; }
            }
            if (ccol == 0) cstv[crow + r] = bestc;
        }
    }
    __syncthreads();

    #pragma unroll
    for (int it = 0; it < 8; ++it) {
        int i4 = it * 256 + tid;
        int r = i4 >> 7, d4 = (i4 & 127) * 4;
        long gi = (long)(m0 + r) * 512 + d4;
        f32x4 fv = *(const f32x4*)(feat + gi);
        f32x4 hv = *(const f32x4*)(hbuf + gi);
        f32x4 iv = *(const f32x4*)(im + (long)cstv[r] * 512 + d4);
        s16x4 o;
        #pragma unroll
        for (int jj = 0; jj < 4; ++jj) {
            float v = (fv[jj] > 0.f) ? -2.f * (hv[jj] - iv[jj]) : 0.f;
            o[jj] = f2bf(v);
        }
        *(s16x4*)(dz_b + gi) = o;
    }
}

// ---------------- tail B: s = feat.h per row; out = 2*(h@mu^T) - s - q ----------------
__global__ __launch_bounds__(256) void tail_b(
    const short* __restrict__ h_b, const short* __restrict__ mu_b,
    const float* __restrict__ feat, const float* __restrict__ hbuf,
    const float* __restrict__ q, float* __restrict__ out)
{
    __shared__ f32x4 red[4][7][64];
    __shared__ float srow[16];
    const int tid = threadIdx.x, lane = tid & 63, w = tid >> 6;
    const int m0 = blockIdx.x * 16;
    const int arow = lane & 15, kseg = lane >> 4;

    #pragma unroll
    for (int rr = 0; rr < 4; ++rr) {
        int r = w * 4 + rr;
        long gi = (long)(m0 + r) * 512 + lane * 8;
        f32x4 a0 = *(const f32x4*)(feat + gi);
        f32x4 a1 = *(const f32x4*)(feat + gi + 4);
        f32x4 b0 = *(const f32x4*)(hbuf + gi);
        f32x4 b1 = *(const f32x4*)(hbuf + gi + 4);
        float ss = 0.f;
        #pragma unroll
        for (int jj = 0; jj < 4; ++jj) ss += a0[jj] * b0[jj] + a1[jj] * b1[jj];
        #pragma unroll
        for (int off = 32; off; off >>= 1) ss += __shfl_down(ss, off);
        if (lane == 0) srow[r] = ss;
    }

    f32x4 acc[7];
    #pragma unroll
    for (int j = 0; j < 7; ++j) acc[j] = f32x4{0.f, 0.f, 0.f, 0.f};
    const long abase = (long)(m0 + arow) * 512 + w * 128 + kseg * 8;
    const long bbase = (long)arow * 512 + w * 128 + kseg * 8;
    #pragma unroll
    for (int kt = 0; kt < 4; ++kt) {
        s16x8 av = *(const s16x8*)(h_b + abase + kt * 32);
        #pragma unroll
        for (int j = 0; j < 7; ++j) {
            s16x8 bv = *(const s16x8*)(mu_b + bbase + (long)j * 16 * 512 + kt * 32);
            acc[j] = __builtin_amdgcn_mfma_f32_16x16x32_bf16(av, bv, acc[j], 0, 0, 0);
        }
    }
    #pragma unroll
    for (int j = 0; j < 7; ++j) red[w][j][lane] = acc[j];
    __syncthreads();

    if (w == 0) {
        const int crow = (lane >> 4) * 4, ccol = lane & 15;
        #pragma unroll
        for (int j = 0; j < 7; ++j) {
            int n = j * 16 + ccol;
            if (n >= 100) continue;
            f32x4 s0 = red[0][j][lane];
            #pragma unroll
            for (int ww = 1; ww < 4; ++ww) s0 += red[ww][j][lane];
            float qn = q[n];
            #pragma unroll
            for (int r = 0; r < 4; ++r)
                out[(long)(m0 + crow + r) * 100 + n] = 2.f * s0[r] - srow[crow + r] - qn;
        }
    }
}

extern "C" void kernel_launch(void* const* d_in, const int* in_sizes, int n_in,
                              void* d_out, int out_size, void* d_ws, size_t ws_size,
                              hipStream_t stream)
{
    const float* x      = (const float*)d_in[0];
    const float* W      = (const float*)d_in[1];
    const float* bias   = (const float*)d_in[2];
    const float* mu     = (const float*)d_in[3];
    const float* invsig = (const float*)d_in[4];
    float* out = (float*)d_out;

    char* wp = (char*)d_ws;
    auto alloc = [&](size_t bytes) { char* p = wp; wp += (bytes + 255) & ~size_t(255); return p; };
    short* x_b   = (short*)alloc((size_t)Bb * INn * 2);
    short* Wt_b  = (short*)alloc((size_t)Dd * INn * 2);
    short* is_b  = (short*)alloc((size_t)Dd * Dd * 2);
    short* mu_b  = (short*)alloc((size_t)112 * Dd * 2);   // zero-padded to 112 rows
    short* wtw_b = (short*)alloc((size_t)Dd * Dd * 2);
    float* im    = (float*)alloc((size_t)Cc * Dd * 4);
    float* q     = (float*)alloc(512);
    float* part  = (float*)alloc((size_t)4 * Bb * Dd * 4);
    float* wpart = (float*)alloc((size_t)4 * Dd * Dd * 4);
    float* featpre = (float*)alloc((size_t)Bb * Dd * 4);
    float* feat  = (float*)alloc((size_t)Bb * Dd * 4);
    short* f_b   = (short*)alloc((size_t)Bb * Dd * 2);
    float* hbuf  = (float*)alloc((size_t)Bb * Dd * 4);
    short* h_b   = (short*)alloc((size_t)Bb * Dd * 2);
    short* dz_b  = (short*)alloc((size_t)Bb * Dd * 2);

    dim3 blk(256);

    // 1. bf16 planes + W transpose
    prep_kernel<<<512, blk, 0, stream>>>(x, W, invsig, mu, x_b, Wt_b, is_b, mu_b);
    // 2. im (fp32 exact) + q
    im_q_kernel<<<Cc, blk, 0, stream>>>(mu, invsig, im, q);
    // 3. WtW partials: Wt@Wt^T split-K4 (128 blocks)
    gemm_b1<0><<<dim3(8, 4, 4), blk, 0, stream>>>(
        Wt_b, Wt_b, wpart, INn, INn / 4, Dd, (long)Dd * Dd, nullptr, nullptr, nullptr, 0.f);
    // 4. reduce WtW -> bf16
    reduce_wtw<<<256, blk, 0, stream>>>(wpart, wtw_b);
    // 5. feat partials: x@W split-K4 (256 blocks)
    gemm_b1<0><<<dim3(8, 8, 4), blk, 0, stream>>>(
        x_b, Wt_b, part, INn, INn / 4, Dd, (long)Bb * Dd, nullptr, nullptr, nullptr, 0.f);
    // 6. reduce + bias + relu -> featpre, feat, f_b
    reduce_feat<<<512, blk, 0, stream>>>(part, bias, featpre, feat, f_b);
    // 7. h = feat @ invsig
    gemm_b1<1><<<dim3(8, 8), blk, 0, stream>>>(
        f_b, is_b, hbuf, Dd, Dd, Dd, 0, nullptr, nullptr, h_b, 0.f);
    // 8. t + argmax + dz
    tail_a<<<Bb / 16, blk, 0, stream>>>(h_b, mu_b, feat, hbuf, im, q, dz_b);
    // 9. feat2 = relu(featpre + bias + eps * dz@WtW)   [linearized FGSM]
    gemm_b1<3><<<dim3(8, 8), blk, 0, stream>>>(
        dz_b, wtw_b, feat, Dd, Dd, Dd, 0, featpre, bias, f_b, EPS_ODIN);
    // 10. h2 = feat2 @ invsig
    gemm_b1<1><<<dim3(8, 8), blk, 0, stream>>>(
        f_b, is_b, hbuf, Dd, Dd, Dd, 0, nullptr, nullptr, h_b, 0.f);
    // 11. s + out
    tail_b<<<Bb / 16, blk, 0, stream>>>(h_b, mu_b, feat, hbuf, q, out);
}